// Round 2
// baseline (682.594 us; speedup 1.0000x reference)
//
#include <hip/hip_runtime.h>

typedef __bf16 bf16x8 __attribute__((ext_vector_type(8)));
typedef float f32x4 __attribute__((ext_vector_type(4)));

typedef const __attribute__((address_space(1))) unsigned int* as1_u32_ptr;
typedef __attribute__((address_space(3))) unsigned int* as3_u32_ptr;

__device__ __forceinline__ void gload_lds16(const void* g, void* l) {
    __builtin_amdgcn_global_load_lds((as1_u32_ptr)g, (as3_u32_ptr)l, 16, 0, 0);
}

__device__ __forceinline__ unsigned short f2bf(float f) {
    unsigned u = __float_as_uint(f);
    u += 0x7fffu + ((u >> 16) & 1u);   // RNE
    return (unsigned short)(u >> 16);
}

// ---------------------------------------------------------------------------
__global__ void cast_f32_bf16(const float* __restrict__ src,
                              unsigned short* __restrict__ dst, int n4) {
    int i = blockIdx.x * 256 + threadIdx.x;
    if (i < n4) {
        float4 v = ((const float4*)src)[i];
        ushort4 o;
        o.x = f2bf(v.x); o.y = f2bf(v.y); o.z = f2bf(v.z); o.w = f2bf(v.w);
        ((ushort4*)dst)[i] = o;
    }
}

// task_mats [8][K][N] f32 -> tasksT [8][N][K] bf16
__global__ void transpose_cast(const float* __restrict__ src,
                               unsigned short* __restrict__ dst) {
    __shared__ float tile[32][33];
    const int j = blockIdx.z;
    const float* M = src + (size_t)j * 1048576;
    unsigned short* Mt = dst + (size_t)j * 1048576;
    const int n0 = blockIdx.x * 32, k0 = blockIdx.y * 32;
    const int tx = threadIdx.x, ty = threadIdx.y;
#pragma unroll
    for (int r = 0; r < 32; r += 8)
        tile[ty + r][tx] = M[(size_t)(k0 + ty + r) * 1024 + n0 + tx];
    __syncthreads();
#pragma unroll
    for (int r = 0; r < 32; r += 8)
        Mt[(size_t)(n0 + ty + r) * 1024 + k0 + tx] = f2bf(tile[tx][ty + r]);
}

// coeff[b][t] = b2[t] + dot(h[b,:], W2[t,:])
__global__ void coeff_kernel(const float* __restrict__ h, const float* __restrict__ W2,
                             const float* __restrict__ b2, float* __restrict__ coeff) {
    __shared__ float w2s[2048];
    const int tid = threadIdx.x;
    for (int i = tid; i < 2048; i += 256) w2s[i] = W2[i];
    __syncthreads();
    const int t = tid & 7;
    const int b = blockIdx.x * 32 + (tid >> 3);
    const float* hr = h + (size_t)b * 256;
    const float* wr = w2s + t * 256;
    float s = b2[t];
#pragma unroll 8
    for (int i = 0; i < 256; ++i) s += hr[i] * wr[i];
    coeff[b * 8 + t] = s;
}

// ---------------------------------------------------------------------------
// metanet: h = relu(X @ W1^T + b1), 128x128 tile (round-1 validated structure)
__launch_bounds__(256, 2)
__global__ void metanet_gemm(const unsigned short* __restrict__ A,
                             const unsigned short* __restrict__ Bt,
                             int M, int N, int K,
                             const float* __restrict__ bias,
                             float* __restrict__ outf) {
    __shared__ __align__(16) unsigned short As[128 * 64];
    __shared__ __align__(16) unsigned short Bs[128 * 64];
    const int tid = threadIdx.x;
    const int wid = tid >> 6, lane = tid & 63;
    const int s = lane & 15, q = lane >> 4;
    const int wm = (wid >> 1) * 64, wn = (wid & 1) * 64;
    const int bm = blockIdx.y * 128, bn = blockIdx.x * 128;
    f32x4 acc[4][4] = {};
    const int rsub = lane >> 3;
    const int usw = ((lane & 7) ^ rsub) * 8;
    const unsigned short* Ag = A + (size_t)(bm + rsub) * K + usw;
    const unsigned short* Bg = Bt + (size_t)(bn + rsub) * K + usw;
    const int c0 = wid * 4;
    for (int k0 = 0; k0 < K; k0 += 64) {
        __syncthreads();
#pragma unroll
        for (int i = 0; i < 4; ++i) {
            const int c = c0 + i;
            gload_lds16(Ag + (size_t)(c * 8) * K + k0, As + c * 512);
            gload_lds16(Bg + (size_t)(c * 8) * K + k0, Bs + c * 512);
        }
        __syncthreads();
#pragma unroll
        for (int kk = 0; kk < 64; kk += 32) {
            bf16x8 av[4], bv[4];
            const int ub = kk >> 3;
#pragma unroll
            for (int t = 0; t < 4; ++t) {
                const int ua = ((ub + q) ^ (s & 7)) * 8;
                av[t] = *(const bf16x8*)(As + (wm + t * 16 + s) * 64 + ua);
                bv[t] = *(const bf16x8*)(Bs + (wn + t * 16 + s) * 64 + ua);
            }
#pragma unroll
            for (int mi = 0; mi < 4; ++mi)
#pragma unroll
                for (int ni = 0; ni < 4; ++ni)
                    acc[mi][ni] = __builtin_amdgcn_mfma_f32_16x16x32_bf16(
                        av[mi], bv[ni], acc[mi][ni], 0, 0, 0);
        }
    }
    const int colb = bn + wn + s;
#pragma unroll
    for (int mi = 0; mi < 4; ++mi) {
        const int row0 = bm + wm + mi * 16 + q * 4;
#pragma unroll
        for (int ni = 0; ni < 4; ++ni) {
            const int col = colb + ni * 16;
#pragma unroll
            for (int r = 0; r < 4; ++r) {
                float v = acc[mi][ni][r] + bias[col];
                outf[(size_t)(row0 + r) * N + col] = v > 0.f ? v : 0.f;
            }
        }
    }
}

// ---------------------------------------------------------------------------
// persistent steps kernel helpers

__device__ __forceinline__ void grid_barrier(int* cnt, int target) {
    __syncthreads();
    if (threadIdx.x == 0) {
        __threadfence();   // release: flush our Xb writes to device scope
        __hip_atomic_fetch_add(cnt, 1, __ATOMIC_ACQ_REL, __HIP_MEMORY_SCOPE_AGENT);
        while (__hip_atomic_load(cnt, __ATOMIC_ACQUIRE, __HIP_MEMORY_SCOPE_AGENT) < target)
            __builtin_amdgcn_s_sleep(8);
    }
    __syncthreads();
    __threadfence();       // acquire: invalidate L1 before reading peers' writes
}

// one 128x128 x K=1024 bf16 MFMA tile-GEMM, double-buffered LDS
__device__ __forceinline__ void gemm_tile(const unsigned short* __restrict__ Ag,
                                          const unsigned short* __restrict__ Bg,
                                          unsigned short* As, unsigned short* Bs,
                                          int c0, int s, int q, int wm, int wn,
                                          f32x4 acc[4][4]) {
#pragma unroll
    for (int i = 0; i < 4; ++i) {   // stage iter 0 -> buf 0
        const int c = c0 + i;
        gload_lds16(Ag + (size_t)(c * 8) * 1024, As + c * 512);
        gload_lds16(Bg + (size_t)(c * 8) * 1024, Bs + c * 512);
    }
#pragma unroll 1
    for (int it = 0; it < 16; ++it) {
        __syncthreads();   // drains buf[it&1] loads (issued 1 full iter ago)
        if (it + 1 < 16) {
            const int nxt = ((it + 1) & 1) * 8192;
            const unsigned short* a = Ag + (it + 1) * 64;
            const unsigned short* b = Bg + (it + 1) * 64;
#pragma unroll
            for (int i = 0; i < 4; ++i) {
                const int c = c0 + i;
                gload_lds16(a + (size_t)(c * 8) * 1024, As + nxt + c * 512);
                gload_lds16(b + (size_t)(c * 8) * 1024, Bs + nxt + c * 512);
            }
        }
        const unsigned short* as = As + (it & 1) * 8192;
        const unsigned short* bs = Bs + (it & 1) * 8192;
#pragma unroll
        for (int kk = 0; kk < 64; kk += 32) {
            bf16x8 av[4], bv[4];
            const int ub = kk >> 3;
#pragma unroll
            for (int t = 0; t < 4; ++t) {
                const int ua = ((ub + q) ^ (s & 7)) * 8;
                av[t] = *(const bf16x8*)(as + (wm + t * 16 + s) * 64 + ua);
                bv[t] = *(const bf16x8*)(bs + (wn + t * 16 + s) * 64 + ua);
            }
#pragma unroll
            for (int mi = 0; mi < 4; ++mi)
#pragma unroll
                for (int ni = 0; ni < 4; ++ni)
                    acc[mi][ni] = __builtin_amdgcn_mfma_f32_16x16x32_bf16(
                        av[mi], bv[ni], acc[mi][ni], 0, 0, 0);
        }
    }
}

// persistent: 8 steps + final projection; fp32 master in registers.
// grid (8,32) = 256 blocks = 1/CU (co-resident); XCD-swizzled tile assignment.
__global__ __launch_bounds__(256, 1) void steps_kernel(
    const float* __restrict__ features,
    const unsigned short* __restrict__ tasksT,
    const unsigned short* __restrict__ WpT,
    const float* __restrict__ coeff,
    unsigned short* __restrict__ Xb0,
    unsigned short* __restrict__ Xb1,
    float* __restrict__ out,
    int* __restrict__ cnt) {
    __shared__ __align__(16) unsigned short As[2 * 8192];
    __shared__ __align__(16) unsigned short Bs[2 * 8192];

    const int tid = threadIdx.x;
    const int wid = tid >> 6, lane = tid & 63;
    const int s = lane & 15, q = lane >> 4;
    const int wm = (wid >> 1) * 64, wn = (wid & 1) * 64;

    // XCD swizzle: linear%8 ~ XCD; each XCD gets 8 row-tiles x 4 col-tiles
    // -> per-XCD working set A 2MB + B 1MB fits 4MB L2. Heuristic only.
    const int L = blockIdx.x + gridDim.x * blockIdx.y;
    const int xcd = L & 7, slot = L >> 3;
    const int bm = ((xcd >> 1) * 8 + (slot & 7)) * 128;
    const int bn = ((xcd & 1) * 4 + (slot >> 3)) * 128;

    const int rsub = lane >> 3;
    const int usw = ((lane & 7) ^ rsub) * 8;
    const int c0 = wid * 4;
    const size_t abase = (size_t)(bm + rsub) * 1024 + usw;
    const size_t bbase = (size_t)(bn + rsub) * 1024 + usw;

    // fp32 master tile: 64 floats/thread, lives in VGPRs for the whole kernel
    float mst[4][4][4];
#pragma unroll
    for (int mi = 0; mi < 4; ++mi) {
        const int row0 = bm + wm + mi * 16 + q * 4;
#pragma unroll
        for (int ni = 0; ni < 4; ++ni) {
            const int col = bn + wn + s + ni * 16;
#pragma unroll
            for (int r = 0; r < 4; ++r)
                mst[mi][ni][r] = features[(size_t)(row0 + r) * 1024 + col];
        }
    }

#pragma unroll 1
    for (int j = 0; j < 8; ++j) {
        if (j > 0) grid_barrier(cnt, 256 * j);
        const unsigned short* Ag = ((j & 1) ? Xb1 : Xb0) + abase;
        const unsigned short* Bg = tasksT + (size_t)j * 1048576 + bbase;
        f32x4 acc[4][4] = {};
        gemm_tile(Ag, Bg, As, Bs, c0, s, q, wm, wn, acc);

        unsigned short* Xn = (j & 1) ? Xb0 : Xb1;   // X_{j+1} -> buf[(j+1)&1]
#pragma unroll
        for (int mi = 0; mi < 4; ++mi) {
            const int row0 = bm + wm + mi * 16 + q * 4;
            float cf[4];
#pragma unroll
            for (int r = 0; r < 4; ++r) cf[r] = coeff[(size_t)(row0 + r) * 8 + j];
#pragma unroll
            for (int ni = 0; ni < 4; ++ni) {
                const int col = bn + wn + s + ni * 16;
#pragma unroll
                for (int r = 0; r < 4; ++r) {
                    mst[mi][ni][r] += cf[r] * acc[mi][ni][r];
                    Xn[(size_t)(row0 + r) * 1024 + col] = f2bf(mst[mi][ni][r]);
                }
            }
        }
    }

    grid_barrier(cnt, 256 * 8);
    {   // final projection: out = X8 @ Wp^T  (X8 bf16 is in Xb0)
        const unsigned short* Ag = Xb0 + abase;
        const unsigned short* Bg = WpT + bbase;
        f32x4 acc[4][4] = {};
        gemm_tile(Ag, Bg, As, Bs, c0, s, q, wm, wn, acc);
#pragma unroll
        for (int mi = 0; mi < 4; ++mi) {
            const int row0 = bm + wm + mi * 16 + q * 4;
#pragma unroll
            for (int ni = 0; ni < 4; ++ni) {
                const int col = bn + wn + s + ni * 16;
#pragma unroll
                for (int r = 0; r < 4; ++r)
                    out[(size_t)(row0 + r) * 1024 + col] = acc[mi][ni][r];
            }
        }
    }
}

// ---------------------------------------------------------------------------
extern "C" void kernel_launch(void* const* d_in, const int* in_sizes, int n_in,
                              void* d_out, int out_size, void* d_ws, size_t ws_size,
                              hipStream_t stream) {
    const float* features = (const float*)d_in[0];  // [4096][1024]
    const float* W1 = (const float*)d_in[1];        // [256][1024]
    const float* b1 = (const float*)d_in[2];        // [256]
    const float* W2 = (const float*)d_in[3];        // [8][256]
    const float* b2 = (const float*)d_in[4];        // [8]
    const float* task = (const float*)d_in[5];      // [8][1024][1024]
    const float* Wp = (const float*)d_in[6];        // [1024][1024]

    char* ws = (char*)d_ws;
    unsigned short* tasksT = (unsigned short*)(ws);             // 16 MB
    unsigned short* Wpbf   = (unsigned short*)(ws + 16777216);  //  2 MB
    unsigned short* W1bf   = (unsigned short*)(ws + 18874368);  // .5 MB
    unsigned short* Xb0    = (unsigned short*)(ws + 19398656);  //  8 MB
    unsigned short* Xb1    = (unsigned short*)(ws + 27787264);  //  8 MB
    float* h               = (float*)(ws + 36175872);           //  4 MB
    float* coeffp          = (float*)(ws + 40370176);           // 128 KB
    int*   cnt             = (int*)(ws + 40501248);             // barrier counter
    float* outf32 = (float*)d_out;

    hipMemsetAsync(cnt, 0, 64, stream);

    cast_f32_bf16<<<4096, 256, 0, stream>>>(features, Xb0, 1048576);
    cast_f32_bf16<<<256, 256, 0, stream>>>(W1, W1bf, 65536);
    cast_f32_bf16<<<1024, 256, 0, stream>>>(Wp, Wpbf, 262144);
    transpose_cast<<<dim3(32, 32, 8), dim3(32, 8, 1), 0, stream>>>(task, tasksT);

    metanet_gemm<<<dim3(2, 32), 256, 0, stream>>>(Xb0, W1bf, 4096, 256, 1024, b1, h);
    coeff_kernel<<<128, 256, 0, stream>>>(h, W2, b2, coeffp);

    steps_kernel<<<dim3(8, 32), 256, 0, stream>>>(features, tasksT, Wpbf, coeffp,
                                                  Xb0, Xb1, outf32, cnt);
}

// Round 3
// 312.619 us; speedup vs baseline: 2.1835x; 2.1835x over previous
//
#include <hip/hip_runtime.h>

// R3: revert to R1's per-launch structure (R2 persistent kernel regressed:
// 1 block/CU + grid barriers + device fences = fully exposed latency).
// Change vs R1: step/final/metanet GEMMs re-tiled 128x128 -> 64x128 so the
// 4096x1024 GEMM launches 512 blocks = 2 blocks/CU for cross-block overlap.

typedef __bf16 bf16x8 __attribute__((ext_vector_type(8)));
typedef float f32x4 __attribute__((ext_vector_type(4)));

typedef const __attribute__((address_space(1))) unsigned int* as1_u32_ptr;
typedef __attribute__((address_space(3))) unsigned int* as3_u32_ptr;

__device__ __forceinline__ void gload_lds16(const void* g, void* l) {
    __builtin_amdgcn_global_load_lds((as1_u32_ptr)g, (as3_u32_ptr)l, 16, 0, 0);
}

__device__ __forceinline__ unsigned short f2bf(float f) {
    unsigned u = __float_as_uint(f);
    u += 0x7fffu + ((u >> 16) & 1u);   // RNE
    return (unsigned short)(u >> 16);
}

// ---------------------------------------------------------------------------
__global__ void cast_f32_bf16(const float* __restrict__ src,
                              unsigned short* __restrict__ dst, int n4) {
    int i = blockIdx.x * 256 + threadIdx.x;
    if (i < n4) {
        float4 v = ((const float4*)src)[i];
        ushort4 o;
        o.x = f2bf(v.x); o.y = f2bf(v.y); o.z = f2bf(v.z); o.w = f2bf(v.w);
        ((ushort4*)dst)[i] = o;
    }
}

// task_mats [8][K][N] f32 -> tasksT [8][N][K] bf16
__global__ void transpose_cast(const float* __restrict__ src,
                               unsigned short* __restrict__ dst) {
    __shared__ float tile[32][33];
    const int j = blockIdx.z;
    const float* M = src + (size_t)j * 1048576;
    unsigned short* Mt = dst + (size_t)j * 1048576;
    const int n0 = blockIdx.x * 32, k0 = blockIdx.y * 32;
    const int tx = threadIdx.x, ty = threadIdx.y;
#pragma unroll
    for (int r = 0; r < 32; r += 8)
        tile[ty + r][tx] = M[(size_t)(k0 + ty + r) * 1024 + n0 + tx];
    __syncthreads();
#pragma unroll
    for (int r = 0; r < 32; r += 8)
        Mt[(size_t)(n0 + ty + r) * 1024 + k0 + tx] = f2bf(tile[tx][ty + r]);
}

// coeff[b][t] = b2[t] + dot(h[b,:], W2[t,:])
__global__ void coeff_kernel(const float* __restrict__ h, const float* __restrict__ W2,
                             const float* __restrict__ b2, float* __restrict__ coeff) {
    __shared__ float w2s[2048];
    const int tid = threadIdx.x;
    for (int i = tid; i < 2048; i += 256) w2s[i] = W2[i];
    __syncthreads();
    const int t = tid & 7;
    const int b = blockIdx.x * 32 + (tid >> 3);
    const float* hr = h + (size_t)b * 256;
    const float* wr = w2s + t * 256;
    float s = b2[t];
#pragma unroll 8
    for (int i = 0; i < 256; ++i) s += hr[i] * wr[i];
    coeff[b * 8 + t] = s;
}

// ---------------------------------------------------------------------------
// GEMM: out = A[M][K](bf16) x Bt[N][K](bf16)^T, 64x128 tile, BK=64, 4 waves
// (2x2, wave tile 32x64), 16x16x32 bf16 MFMA, global_load_lds w16, XOR-swizzled
// LDS. Grid dim3(N/128, M/64) -> 512 blocks for M=4096,N=1024 = 2 blocks/CU.
// MODE 0 (H):     outf = relu(acc + bias[n])
// MODE 1 (STEP):  v = xf32 + coeff[row*8+j]*acc ; outf = v ; outb = bf16(v)
// MODE 2 (FINAL): outf = acc
template <int MODE>
__launch_bounds__(256, 2)
__global__ void gemm_kernel(const unsigned short* __restrict__ A,
                            const unsigned short* __restrict__ Bt,
                            int M, int N, int K,
                            const float* __restrict__ xf32,
                            const float* __restrict__ coeff, int jidx,
                            const float* __restrict__ bias,
                            float* __restrict__ outf,
                            unsigned short* __restrict__ outb) {
    __shared__ __align__(16) unsigned short As[64 * 64];    //  8 KB
    __shared__ __align__(16) unsigned short Bs[128 * 64];   // 16 KB

    const int tid = threadIdx.x;
    const int wid = tid >> 6;
    const int lane = tid & 63;
    const int s = lane & 15, q = lane >> 4;
    const int wm = (wid >> 1) * 32, wn = (wid & 1) * 64;
    const int bm = blockIdx.y * 64, bn = blockIdx.x * 128;

    f32x4 acc[2][4] = {};

    // staging: chunk = 8 rows x 64 els (1 KB); lane covers row chunk*8+(lane>>3),
    // swizzled 16B unit: u_log = (lane&7) ^ (lane>>3).  A: 8 chunks (2/wave),
    // B: 16 chunks (4/wave).
    const int rsub = lane >> 3;
    const int usw = ((lane & 7) ^ rsub) * 8;
    const unsigned short* Ag = A + (size_t)(bm + rsub) * K + usw;
    const unsigned short* Bg = Bt + (size_t)(bn + rsub) * K + usw;
    const int ca0 = wid * 2, cb0 = wid * 4;

    for (int k0 = 0; k0 < K; k0 += 64) {
        __syncthreads();   // previous tile fully consumed
#pragma unroll
        for (int i = 0; i < 2; ++i) {
            const int c = ca0 + i;
            gload_lds16(Ag + (size_t)(c * 8) * K + k0, As + c * 512);
        }
#pragma unroll
        for (int i = 0; i < 4; ++i) {
            const int c = cb0 + i;
            gload_lds16(Bg + (size_t)(c * 8) * K + k0, Bs + c * 512);
        }
        __syncthreads();   // drain vmcnt(0) before s_barrier

#pragma unroll
        for (int kk = 0; kk < 64; kk += 32) {
            bf16x8 av[2], bv[4];
            const int ub = kk >> 3;
            const int ua = ((ub + q) ^ (s & 7)) * 8;
#pragma unroll
            for (int t = 0; t < 2; ++t)
                av[t] = *(const bf16x8*)(As + (wm + t * 16 + s) * 64 + ua);
#pragma unroll
            for (int t = 0; t < 4; ++t)
                bv[t] = *(const bf16x8*)(Bs + (wn + t * 16 + s) * 64 + ua);
#pragma unroll
            for (int mi = 0; mi < 2; ++mi)
#pragma unroll
                for (int ni = 0; ni < 4; ++ni)
                    acc[mi][ni] = __builtin_amdgcn_mfma_f32_16x16x32_bf16(
                        av[mi], bv[ni], acc[mi][ni], 0, 0, 0);
        }
    }

    // epilogue: C/D layout col = lane&15, row = (lane>>4)*4 + reg  [m89-verified]
    const int colb = bn + wn + s;
#pragma unroll
    for (int mi = 0; mi < 2; ++mi) {
        const int row0 = bm + wm + mi * 16 + q * 4;
        float cf[4];
        if (MODE == 1) {
#pragma unroll
            for (int r = 0; r < 4; ++r) cf[r] = coeff[(size_t)(row0 + r) * 8 + jidx];
        }
#pragma unroll
        for (int ni = 0; ni < 4; ++ni) {
            const int col = colb + ni * 16;
#pragma unroll
            for (int r = 0; r < 4; ++r) {
                const size_t off = (size_t)(row0 + r) * N + col;
                float v = acc[mi][ni][r];
                if (MODE == 0) {
                    v += bias[col];
                    v = v > 0.f ? v : 0.f;
                    outf[off] = v;
                } else if (MODE == 1) {
                    v = xf32[off] + cf[r] * v;
                    outf[off] = v;
                    outb[off] = f2bf(v);
                } else {
                    outf[off] = v;
                }
            }
        }
    }
}

// ---------------------------------------------------------------------------
extern "C" void kernel_launch(void* const* d_in, const int* in_sizes, int n_in,
                              void* d_out, int out_size, void* d_ws, size_t ws_size,
                              hipStream_t stream) {
    const float* features = (const float*)d_in[0];  // [4096][1024]
    const float* W1 = (const float*)d_in[1];        // [256][1024]
    const float* b1 = (const float*)d_in[2];        // [256]
    const float* W2 = (const float*)d_in[3];        // [8][256]
    const float* b2 = (const float*)d_in[4];        // [8]
    const float* task = (const float*)d_in[5];      // [8][1024][1024]
    const float* Wp = (const float*)d_in[6];        // [1024][1024]

    char* ws = (char*)d_ws;
    unsigned short* tasksT = (unsigned short*)(ws);             // 16 MB
    unsigned short* Wpbf   = (unsigned short*)(ws + 16777216);  //  2 MB
    unsigned short* W1bf   = (unsigned short*)(ws + 18874368);  // .5 MB
    unsigned short* Xbf0   = (unsigned short*)(ws + 19398656);  //  8 MB
    unsigned short* Xbf1   = (unsigned short*)(ws + 27787264);  //  8 MB
    float* F0              = (float*)(ws + 36175872);           // 16 MB fp32 master ping
    float* coeffp          = (float*)(ws + 52953088);           // 128 KB
    float* h               = (float*)(ws + 36175872);           // alias F0 (dead before step0 writes)
    float* outf32 = (float*)d_out;                              // fp32 master pong + final out

    cast_f32_bf16<<<4096, 256, 0, stream>>>(features, Xbf0, 1048576);
    cast_f32_bf16<<<256, 256, 0, stream>>>(W1, W1bf, 65536);
    cast_f32_bf16<<<1024, 256, 0, stream>>>(Wp, Wpbf, 262144);
    transpose_cast<<<dim3(32, 32, 8), dim3(32, 8, 1), 0, stream>>>(task, tasksT);

    // metanet: h = relu(X @ W1^T + b1)  [4096 x 256] -> grid (2,64) = 128 blocks
    gemm_kernel<0><<<dim3(2, 64), 256, 0, stream>>>(Xbf0, W1bf, 4096, 256, 1024,
                                                    nullptr, nullptr, 0, b1, h, nullptr);
    coeff_kernel<<<128, 256, 0, stream>>>(h, W2, b2, coeffp);

    // 8 sequential soft task-vector steps: grid (8,64) = 512 blocks = 2/CU
    for (int j = 0; j < 8; ++j) {
        const unsigned short* Abf = (j & 1) ? Xbf1 : Xbf0;
        unsigned short* Obf = (j & 1) ? Xbf0 : Xbf1;
        const float* xin = (j == 0) ? features : ((j & 1) ? F0 : outf32);
        float* xout = (j & 1) ? outf32 : F0;
        gemm_kernel<1><<<dim3(8, 64), 256, 0, stream>>>(
            Abf, tasksT + (size_t)j * 1048576, 4096, 1024, 1024,
            xin, coeffp, j, nullptr, xout, Obf);
    }

    // final projection: out = X8 @ Wp^T   (A = Xbf0 after step 7)
    gemm_kernel<2><<<dim3(8, 64), 256, 0, stream>>>(Xbf0, Wpbf, 4096, 1024, 1024,
                                                    nullptr, nullptr, 0, nullptr,
                                                    outf32, nullptr);
}

// Round 4
// 302.048 us; speedup vs baseline: 2.2599x; 1.0350x over previous
//
#include <hip/hip_runtime.h>

// R4: 64x64 step-GEMM tile -> grid 1024 = 4 blocks/CU (16 waves/CU) so the
// K-loop barrier drain of one block is covered by 3 others' MFMA phases.
// R3 (64x128, 2/CU) = 312 us, still latency-bound (MfmaUtil/VALU/HBM all low).

typedef __bf16 bf16x8 __attribute__((ext_vector_type(8)));
typedef float f32x4 __attribute__((ext_vector_type(4)));

typedef const __attribute__((address_space(1))) unsigned int* as1_u32_ptr;
typedef __attribute__((address_space(3))) unsigned int* as3_u32_ptr;

__device__ __forceinline__ void gload_lds16(const void* g, void* l) {
    __builtin_amdgcn_global_load_lds((as1_u32_ptr)g, (as3_u32_ptr)l, 16, 0, 0);
}

__device__ __forceinline__ unsigned short f2bf(float f) {
    unsigned u = __float_as_uint(f);
    u += 0x7fffu + ((u >> 16) & 1u);   // RNE
    return (unsigned short)(u >> 16);
}

// ---------------------------------------------------------------------------
__global__ void cast_f32_bf16(const float* __restrict__ src,
                              unsigned short* __restrict__ dst, int n4) {
    int i = blockIdx.x * 256 + threadIdx.x;
    if (i < n4) {
        float4 v = ((const float4*)src)[i];
        ushort4 o;
        o.x = f2bf(v.x); o.y = f2bf(v.y); o.z = f2bf(v.z); o.w = f2bf(v.w);
        ((ushort4*)dst)[i] = o;
    }
}

// task_mats [8][K][N] f32 -> tasksT [8][N][K] bf16
__global__ void transpose_cast(const float* __restrict__ src,
                               unsigned short* __restrict__ dst) {
    __shared__ float tile[32][33];
    const int j = blockIdx.z;
    const float* M = src + (size_t)j * 1048576;
    unsigned short* Mt = dst + (size_t)j * 1048576;
    const int n0 = blockIdx.x * 32, k0 = blockIdx.y * 32;
    const int tx = threadIdx.x, ty = threadIdx.y;
#pragma unroll
    for (int r = 0; r < 32; r += 8)
        tile[ty + r][tx] = M[(size_t)(k0 + ty + r) * 1024 + n0 + tx];
    __syncthreads();
#pragma unroll
    for (int r = 0; r < 32; r += 8)
        Mt[(size_t)(n0 + ty + r) * 1024 + k0 + tx] = f2bf(tile[tx][ty + r]);
}

// coeff[b][t] = b2[t] + dot(h[b,:], W2[t,:])
__global__ void coeff_kernel(const float* __restrict__ h, const float* __restrict__ W2,
                             const float* __restrict__ b2, float* __restrict__ coeff) {
    __shared__ float w2s[2048];
    const int tid = threadIdx.x;
    for (int i = tid; i < 2048; i += 256) w2s[i] = W2[i];
    __syncthreads();
    const int t = tid & 7;
    const int b = blockIdx.x * 32 + (tid >> 3);
    const float* hr = h + (size_t)b * 256;
    const float* wr = w2s + t * 256;
    float s = b2[t];
#pragma unroll 8
    for (int i = 0; i < 256; ++i) s += hr[i] * wr[i];
    coeff[b * 8 + t] = s;
}

// ---------------------------------------------------------------------------
// GEMM: out = A[M][K](bf16) x Bt[N][K](bf16)^T, 64x64 tile, BK=64, 4 waves
// (2x2, wave tile 32x32), 16x16x32 bf16 MFMA, global_load_lds w16, XOR-swizzled
// LDS. Grid dim3(N/64, M/64) -> 1024 blocks for M=4096,N=1024 = 4 blocks/CU.
// MODE 0 (H):     outf = relu(acc + bias[n])
// MODE 1 (STEP):  v = xf32 + coeff[row*8+j]*acc ; outf = v ; outb = bf16(v)
// MODE 2 (FINAL): outf = acc
template <int MODE>
__launch_bounds__(256, 4)
__global__ void gemm_kernel(const unsigned short* __restrict__ A,
                            const unsigned short* __restrict__ Bt,
                            int M, int N, int K,
                            const float* __restrict__ xf32,
                            const float* __restrict__ coeff, int jidx,
                            const float* __restrict__ bias,
                            float* __restrict__ outf,
                            unsigned short* __restrict__ outb) {
    __shared__ __align__(16) unsigned short As[64 * 64];    // 8 KB
    __shared__ __align__(16) unsigned short Bs[64 * 64];    // 8 KB

    const int tid = threadIdx.x;
    const int wid = tid >> 6;
    const int lane = tid & 63;
    const int s = lane & 15, q = lane >> 4;
    const int wm = (wid >> 1) * 32, wn = (wid & 1) * 32;
    const int bm = blockIdx.y * 64, bn = blockIdx.x * 64;

    f32x4 acc[2][2] = {};

    // staging: chunk = 8 rows x 64 els (1 KB); lane covers row chunk*8+(lane>>3),
    // swizzled 16B unit: u_log = (lane&7) ^ (lane>>3). A: 8 chunks, B: 8 chunks,
    // 2 of each per wave.
    const int rsub = lane >> 3;
    const int usw = ((lane & 7) ^ rsub) * 8;
    const unsigned short* Ag = A + (size_t)(bm + rsub) * K + usw;
    const unsigned short* Bg = Bt + (size_t)(bn + rsub) * K + usw;
    const int c0 = wid * 2;

    for (int k0 = 0; k0 < K; k0 += 64) {
        __syncthreads();   // previous tile fully consumed
#pragma unroll
        for (int i = 0; i < 2; ++i) {
            const int c = c0 + i;
            gload_lds16(Ag + (size_t)(c * 8) * K + k0, As + c * 512);
            gload_lds16(Bg + (size_t)(c * 8) * K + k0, Bs + c * 512);
        }
        __syncthreads();   // drain vmcnt(0) before s_barrier

#pragma unroll
        for (int kk = 0; kk < 64; kk += 32) {
            bf16x8 av[2], bv[2];
            const int ub = kk >> 3;
            const int ua = ((ub + q) ^ (s & 7)) * 8;
#pragma unroll
            for (int t = 0; t < 2; ++t) {
                av[t] = *(const bf16x8*)(As + (wm + t * 16 + s) * 64 + ua);
                bv[t] = *(const bf16x8*)(Bs + (wn + t * 16 + s) * 64 + ua);
            }
#pragma unroll
            for (int mi = 0; mi < 2; ++mi)
#pragma unroll
                for (int ni = 0; ni < 2; ++ni)
                    acc[mi][ni] = __builtin_amdgcn_mfma_f32_16x16x32_bf16(
                        av[mi], bv[ni], acc[mi][ni], 0, 0, 0);
        }
    }

    // epilogue: C/D layout col = lane&15, row = (lane>>4)*4 + reg  [m89-verified]
    const int colb = bn + wn + s;
#pragma unroll
    for (int mi = 0; mi < 2; ++mi) {
        const int row0 = bm + wm + mi * 16 + q * 4;
        float cf[4];
        if (MODE == 1) {
#pragma unroll
            for (int r = 0; r < 4; ++r) cf[r] = coeff[(size_t)(row0 + r) * 8 + jidx];
        }
#pragma unroll
        for (int ni = 0; ni < 2; ++ni) {
            const int col = colb + ni * 16;
#pragma unroll
            for (int r = 0; r < 4; ++r) {
                const size_t off = (size_t)(row0 + r) * N + col;
                float v = acc[mi][ni][r];
                if (MODE == 0) {
                    v += bias[col];
                    v = v > 0.f ? v : 0.f;
                    outf[off] = v;
                } else if (MODE == 1) {
                    v = xf32[off] + cf[r] * v;
                    outf[off] = v;
                    outb[off] = f2bf(v);
                } else {
                    outf[off] = v;
                }
            }
        }
    }
}

// ---------------------------------------------------------------------------
extern "C" void kernel_launch(void* const* d_in, const int* in_sizes, int n_in,
                              void* d_out, int out_size, void* d_ws, size_t ws_size,
                              hipStream_t stream) {
    const float* features = (const float*)d_in[0];  // [4096][1024]
    const float* W1 = (const float*)d_in[1];        // [256][1024]
    const float* b1 = (const float*)d_in[2];        // [256]
    const float* W2 = (const float*)d_in[3];        // [8][256]
    const float* b2 = (const float*)d_in[4];        // [8]
    const float* task = (const float*)d_in[5];      // [8][1024][1024]
    const float* Wp = (const float*)d_in[6];        // [1024][1024]

    char* ws = (char*)d_ws;
    unsigned short* tasksT = (unsigned short*)(ws);             // 16 MB
    unsigned short* Wpbf   = (unsigned short*)(ws + 16777216);  //  2 MB
    unsigned short* W1bf   = (unsigned short*)(ws + 18874368);  // .5 MB
    unsigned short* Xbf0   = (unsigned short*)(ws + 19398656);  //  8 MB
    unsigned short* Xbf1   = (unsigned short*)(ws + 27787264);  //  8 MB
    float* F0              = (float*)(ws + 36175872);           // 16 MB fp32 master ping
    float* coeffp          = (float*)(ws + 52953088);           // 128 KB
    float* h               = (float*)(ws + 36175872);           // alias F0 (dead before step0 writes)
    float* outf32 = (float*)d_out;                              // fp32 master pong + final out

    cast_f32_bf16<<<4096, 256, 0, stream>>>(features, Xbf0, 1048576);
    cast_f32_bf16<<<256, 256, 0, stream>>>(W1, W1bf, 65536);
    cast_f32_bf16<<<1024, 256, 0, stream>>>(Wp, Wpbf, 262144);
    transpose_cast<<<dim3(32, 32, 8), dim3(32, 8, 1), 0, stream>>>(task, tasksT);

    // metanet: h = relu(X @ W1^T + b1)  [4096 x 256] -> grid (4,64) = 256 blocks
    gemm_kernel<0><<<dim3(4, 64), 256, 0, stream>>>(Xbf0, W1bf, 4096, 256, 1024,
                                                    nullptr, nullptr, 0, b1, h, nullptr);
    coeff_kernel<<<128, 256, 0, stream>>>(h, W2, b2, coeffp);

    // 8 sequential soft task-vector steps: grid (16,64) = 1024 blocks = 4/CU
    for (int j = 0; j < 8; ++j) {
        const unsigned short* Abf = (j & 1) ? Xbf1 : Xbf0;
        unsigned short* Obf = (j & 1) ? Xbf0 : Xbf1;
        const float* xin = (j == 0) ? features : ((j & 1) ? F0 : outf32);
        float* xout = (j & 1) ? outf32 : F0;
        gemm_kernel<1><<<dim3(16, 64), 256, 0, stream>>>(
            Abf, tasksT + (size_t)j * 1048576, 4096, 1024, 1024,
            xin, coeffp, j, nullptr, xout, Obf);
    }

    // final projection: out = X8 @ Wp^T   (A = Xbf0 after step 7)
    gemm_kernel<2><<<dim3(16, 64), 256, 0, stream>>>(Xbf0, Wpbf, 4096, 1024, 1024,
                                                     nullptr, nullptr, 0, nullptr,
                                                     outf32, nullptr);
}